// Round 2
// baseline (1395.778 us; speedup 1.0000x reference)
//
#include <hip/hip_runtime.h>
#include <hip/hip_cooperative_groups.h>

namespace cg = cooperative_groups;

// Frobenius_71975061946522 — persistent-cooperative version.
// X (4096x4096 fp32 = 64 MB) lives in VGPRs across all 20 iterations:
// 256 blocks x 1024 threads, thread t of block b holds X[16b+r][4t..4t+3],
// r=0..15 -> 16 float4 = 64 VGPRs of data. Row sums are block-local (block
// owns 16 full rows). Only column sums + grand total cross blocks:
// colpart (4 MB) -> 64-block tree reduce -> col_out (16 KB) broadcast,
// with two grid.sync() per iteration.
// __launch_bounds__(1024,4): 4 waves/EU = 16 waves/CU = exactly 1 block/CU,
// caps VGPR at 128 so all 256 blocks are co-resident (cooperative req).

#define NN   4096
#define NV4  1024          // NN/4 float4 per row
#define RPB  16            // rows per block
#define NBLK 256           // NN / RPB
#define ITERS 20
#define INV_N (1.0f / 4096.0f)

__device__ __forceinline__ float wave_reduce_sum(float v) {
    #pragma unroll
    for (int m = 1; m < 64; m <<= 1) v += __shfl_xor(v, m, 64);
    return v;
}

__global__ __launch_bounds__(1024, 4)
void persist_kernel(const float* __restrict__ X0, float* __restrict__ Xout,
                    float* __restrict__ colpart, float* __restrict__ col_out,
                    float* __restrict__ blocktot, float* __restrict__ s_glob)
{
    cg::grid_group grid = cg::this_grid();
    const int t    = threadIdx.x;
    const int wave = t >> 6;
    const int lane = t & 63;
    const int b    = blockIdx.x;
    const int row0 = b * RPB;

    __shared__ float lr[RPB][16];   // [row][wave] row-sum partials
    __shared__ float rs[RPB];       // block's 16 row sums
    __shared__ float csum[16][64];  // col-reduce stage (blocks 0..63)
    __shared__ float ws4[4];        // scalar reduce (block 64)

    // Load this thread's 16 float4 of X into registers.
    float4 x[RPB];
    const float4* x0 = (const float4*)X0;
    #pragma unroll
    for (int r = 0; r < RPB; ++r)
        x[r] = x0[(size_t)(row0 + r) * NV4 + t];

    for (int iter = 0; iter < ITERS; ++iter) {
        // ---- phase 1: row sums (block-local) + column partials ----
        float4 cacc = make_float4(0.f, 0.f, 0.f, 0.f);
        #pragma unroll
        for (int r = 0; r < RPB; ++r) {
            cacc.x += x[r].x; cacc.y += x[r].y;
            cacc.z += x[r].z; cacc.w += x[r].w;
            float rsum = (x[r].x + x[r].y) + (x[r].z + x[r].w);
            rsum = wave_reduce_sum(rsum);
            if (lane == 0) lr[r][wave] = rsum;
        }
        ((float4*)colpart)[(size_t)b * NV4 + t] = cacc;
        __syncthreads();
        if (t < RPB) {
            float s = 0.f;
            #pragma unroll
            for (int w = 0; w < 16; ++w) s += lr[t][w];
            rs[t] = s;
        }
        __syncthreads();
        if (t == 0) {
            float bt = 0.f;
            #pragma unroll
            for (int r = 0; r < RPB; ++r) bt += rs[r];
            blocktot[b] = bt;
        }
        grid.sync();

        // ---- phase 2: cross-block reductions ----
        if (b < 64) {
            // block b reduces columns [64b, 64b+64): 16 waves x 16 partials
            const int jl = t & 63;        // column within the 64-col group
            const int c  = t >> 6;        // which 16-chunk of the 256 partials
            const int j  = b * 64 + jl;
            float p = 0.f;
            #pragma unroll
            for (int k = 0; k < 16; ++k)
                p += colpart[(size_t)(c * 16 + k) * NN + j];
            csum[c][jl] = p;
            __syncthreads();
            if (t < 64) {
                float s = 0.f;
                #pragma unroll
                for (int c2 = 0; c2 < 16; ++c2) s += csum[c2][t];
                col_out[b * 64 + t] = s;
            }
        } else if (b == 64) {
            if (t < 256) {
                float v = blocktot[t];
                v = wave_reduce_sum(v);
                if (lane == 0) ws4[wave] = v;
            }
            __syncthreads();
            if (t == 0) *s_glob = (ws4[0] + ws4[1]) + (ws4[2] + ws4[3]);
        }
        grid.sync();

        // ---- phase 3: in-register update X <- relu(P1(X)) ----
        const float s  = *s_glob;
        const float c0 = INV_N + s * (INV_N * INV_N);
        const float4 cv = ((const float4*)col_out)[t];
        float4 csub;
        csub.x = cv.x * INV_N; csub.y = cv.y * INV_N;
        csub.z = cv.z * INV_N; csub.w = cv.w * INV_N;
        #pragma unroll
        for (int r = 0; r < RPB; ++r) {
            const float a = c0 - rs[r] * INV_N;
            x[r].x = fmaxf(x[r].x + a - csub.x, 0.f);
            x[r].y = fmaxf(x[r].y + a - csub.y, 0.f);
            x[r].z = fmaxf(x[r].z + a - csub.z, 0.f);
            x[r].w = fmaxf(x[r].w + a - csub.w, 0.f);
        }
    }

    // Write the final X.
    float4* xo = (float4*)Xout;
    #pragma unroll
    for (int r = 0; r < RPB; ++r)
        xo[(size_t)(row0 + r) * NV4 + t] = x[r];
}

extern "C" void kernel_launch(void* const* d_in, const int* in_sizes, int n_in,
                              void* d_out, int out_size, void* d_ws, size_t ws_size,
                              hipStream_t stream)
{
    const float* X0 = (const float*)d_in[0];
    float* X  = (float*)d_out;
    float* ws = (float*)d_ws;

    // Workspace (floats): colpart[256*4096] | col_out[4096] | blocktot[256] | s[1]
    float* colpart  = ws;
    float* col_out  = colpart + (size_t)NBLK * NN;
    float* blocktot = col_out + NN;
    float* s_glob   = blocktot + NBLK;

    void* args[] = { (void*)&X0, (void*)&X, (void*)&colpart,
                     (void*)&col_out, (void*)&blocktot, (void*)&s_glob };
    hipLaunchCooperativeKernel((const void*)persist_kernel,
                               dim3(NBLK), dim3(1024), args, 0, stream);
}